// Round 6
// baseline (362.084 us; speedup 1.0000x reference)
//
#include <hip/hip_runtime.h>

// FeatureWithRelativePosition: fused pairwise-dist -> Linear(4096->64) -> LN -> SiLU
// BS=4, N=4096, FEAT=64. fp32 in/out, bf16 MFMA inner product, fp32 accumulate.
//
// R6: NO LDS in the K-loop, NO barriers. Each wave loads its 4 B-fragments
//     directly from the pre-transposed bf16 Wbt (64 consecutive uint4 per read
//     -> perfectly coalesced, L2-resident 512KB) and its 8 k-points from the
//     SoA pos transpose. Waves run unsynchronized; latency hidden by
//     occupancy. LDS (32 KiB) only for the final 8-way K-merge.
//     (R5 was barrier-bound: vmcnt(0) drain before each s_barrier serialized
//     pos-load latency x16 chunks for all waves together.)

typedef float f32x4 __attribute__((ext_vector_type(4)));
typedef __bf16 bf16x8 __attribute__((ext_vector_type(8)));

union BF8 { bf16x8 v; uint4 u; };

#define N_PTS 4096
#define FEATD 64

// ---- prep: blocks 0..127 convert W fp32 -> bf16 granule-major Wbt[512][64][8];
//      blocks 128..143 transpose pos -> Pt[coord][batch][4096] (SoA) ----
__global__ void prep_kernel(const float* __restrict__ W,
                            const float* __restrict__ pos,
                            unsigned short* __restrict__ Wbt,
                            float* __restrict__ Pt) {
  int b = blockIdx.x, t = threadIdx.x;  // 256 threads
  if (b < 128) {
    int gid = b * 256 + t;              // 32768 = 64 f * 512 G
    int f = gid >> 9, m8 = gid & 511;
    const float4* src = (const float4*)(W + (size_t)f * N_PTS + m8 * 8);
    float4 a = src[0], bb = src[1];
    BF8 o;
    o.v[0] = (__bf16)a.x;  o.v[1] = (__bf16)a.y;  o.v[2] = (__bf16)a.z;  o.v[3] = (__bf16)a.w;
    o.v[4] = (__bf16)bb.x; o.v[5] = (__bf16)bb.y; o.v[6] = (__bf16)bb.z; o.v[7] = (__bf16)bb.w;
    ((uint4*)Wbt)[(size_t)m8 * 64 + f] = o.u;
  } else {
    int bb = b - 128;          // 0..15
    int batch = bb >> 2, qtr = bb & 3;
    const float4* p4 = (const float4*)(pos + ((size_t)batch * N_PTS + qtr * 1024) * 3);
    float4 f0 = p4[t * 3 + 0], f1 = p4[t * 3 + 1], f2 = p4[t * 3 + 2];
    float4* Px = (float4*)(Pt + (size_t)(0 * 4 + batch) * N_PTS) + qtr * 256;
    float4* Py = (float4*)(Pt + (size_t)(1 * 4 + batch) * N_PTS) + qtr * 256;
    float4* Pz = (float4*)(Pt + (size_t)(2 * 4 + batch) * N_PTS) + qtr * 256;
    Px[t] = make_float4(f0.x, f0.w, f1.z, f2.y);
    Py[t] = make_float4(f0.y, f1.x, f1.w, f2.z);
    Pz[t] = make_float4(f0.z, f1.y, f2.x, f2.w);
  }
}

// grid = 512 (batch = bid>>7, rowblk = (bid&127)*32), block = 512 thr (8 waves).
// wave = K-slice (512 k each); every wave covers all 32 rows (2 rowtiles x 4 ftiles).
__global__ __launch_bounds__(512, 6) void frp_kernel(
    const float* __restrict__ pos, const float* __restrict__ W,
    const float* __restrict__ bias, const float* __restrict__ gamma,
    const float* __restrict__ beta, const unsigned short* __restrict__ Wbt,
    const float* __restrict__ Pt, float* __restrict__ out) {
  __shared__ f32x4 mbuf[4 * 512];   // 32 KiB merge buffer (4 regions x 8 KiB)

  const int tid = threadIdx.x;
  const int lane = tid & 63;
  const int wave = tid >> 6;       // 0..7 = K-slice
  const int fx = lane & 15;
  const int q = lane >> 4;

  const int batch = blockIdx.x >> 7;
  const int rb = (blockIdx.x & 127) * 32;
  const float* posB = pos + (size_t)batch * N_PTS * 3;
  const bool useWs = (Wbt != nullptr);

  f32x4 acc[2][4];
#pragma unroll
  for (int a = 0; a < 2; ++a)
#pragma unroll
    for (int t = 0; t < 4; ++t) acc[a][t] = (f32x4){0.f, 0.f, 0.f, 0.f};

  const int G0 = wave * 4 + q;     // this lane's first granule (8 k-pts)

  if (useWs) {
    const float* PxG = Pt + (size_t)(0 * 4 + batch) * N_PTS;
    const float* PyG = Pt + (size_t)(1 * 4 + batch) * N_PTS;
    const float* PzG = Pt + (size_t)(2 * 4 + batch) * N_PTS;
    const uint4* Wq = (const uint4*)Wbt;

    // A-row positions (2 rowtiles): rows rb + a*16 + fx
    const int n0 = rb + fx;
    const float px0 = PxG[n0],      py0 = PyG[n0],      pz0 = PzG[n0];
    const float px1 = PxG[n0 + 16], py1 = PyG[n0 + 16], pz1 = PzG[n0 + 16];

#pragma unroll 2
    for (int c = 0; c < 16; ++c) {
      const int G = c * 32 + G0;       // global granule
      const int m4 = G * 2;
      // 8 k-points (VMEM, broadcast within quad, no barrier dependency)
      f32x4 xa = ((const f32x4*)PxG)[m4], xb = ((const f32x4*)PxG)[m4 + 1];
      f32x4 ya = ((const f32x4*)PyG)[m4], yb = ((const f32x4*)PyG)[m4 + 1];
      f32x4 za = ((const f32x4*)PzG)[m4], zb = ((const f32x4*)PzG)[m4 + 1];
      // 4 B-fragments: 64 consecutive uint4 per instr -> coalesced, L2-hit
      const uint4* wg = Wq + (size_t)G * 64 + fx;
      uint4 w0 = wg[0], w1 = wg[16], w2 = wg[32], w3 = wg[48];

      bf16x8 af0, af1;
      {
        f32x4 dx = xa - px0, dy = ya - py0, dz = za - pz0;
        f32x4 sq = dx * dx + dy * dy + dz * dz;
#pragma unroll
        for (int j = 0; j < 4; ++j) af0[j] = (__bf16)__builtin_amdgcn_sqrtf(sq[j]);
        dx = xb - px0; dy = yb - py0; dz = zb - pz0;
        sq = dx * dx + dy * dy + dz * dz;
#pragma unroll
        for (int j = 0; j < 4; ++j) af0[4 + j] = (__bf16)__builtin_amdgcn_sqrtf(sq[j]);
        dx = xa - px1; dy = ya - py1; dz = za - pz1;
        sq = dx * dx + dy * dy + dz * dz;
#pragma unroll
        for (int j = 0; j < 4; ++j) af1[j] = (__bf16)__builtin_amdgcn_sqrtf(sq[j]);
        dx = xb - px1; dy = yb - py1; dz = zb - pz1;
        sq = dx * dx + dy * dy + dz * dz;
#pragma unroll
        for (int j = 0; j < 4; ++j) af1[4 + j] = (__bf16)__builtin_amdgcn_sqrtf(sq[j]);
      }
      BF8 b0, b1, b2, b3;
      b0.u = w0; b1.u = w1; b2.u = w2; b3.u = w3;
      acc[0][0] = __builtin_amdgcn_mfma_f32_16x16x32_bf16(af0, b0.v, acc[0][0], 0, 0, 0);
      acc[1][0] = __builtin_amdgcn_mfma_f32_16x16x32_bf16(af1, b0.v, acc[1][0], 0, 0, 0);
      acc[0][1] = __builtin_amdgcn_mfma_f32_16x16x32_bf16(af0, b1.v, acc[0][1], 0, 0, 0);
      acc[1][1] = __builtin_amdgcn_mfma_f32_16x16x32_bf16(af1, b1.v, acc[1][1], 0, 0, 0);
      acc[0][2] = __builtin_amdgcn_mfma_f32_16x16x32_bf16(af0, b2.v, acc[0][2], 0, 0, 0);
      acc[1][2] = __builtin_amdgcn_mfma_f32_16x16x32_bf16(af1, b2.v, acc[1][2], 0, 0, 0);
      acc[0][3] = __builtin_amdgcn_mfma_f32_16x16x32_bf16(af0, b3.v, acc[0][3], 0, 0, 0);
      acc[1][3] = __builtin_amdgcn_mfma_f32_16x16x32_bf16(af1, b3.v, acc[1][3], 0, 0, 0);
    }
  } else {
    // fallback (harness always provides ws; correctness-only path)
    const int n0 = rb + fx;
    const float px0 = posB[n0 * 3], py0 = posB[n0 * 3 + 1], pz0 = posB[n0 * 3 + 2];
    const float px1 = posB[(n0 + 16) * 3], py1 = posB[(n0 + 16) * 3 + 1],
                pz1 = posB[(n0 + 16) * 3 + 2];
    for (int c = 0; c < 16; ++c) {
      const int G = c * 32 + G0;
      float kx[8], ky[8], kz[8];
#pragma unroll
      for (int j = 0; j < 8; ++j) {
        const float* pk = posB + ((size_t)G * 8 + j) * 3;
        kx[j] = pk[0]; ky[j] = pk[1]; kz[j] = pk[2];
      }
      bf16x8 af0, af1;
#pragma unroll
      for (int j = 0; j < 8; ++j) {
        float dx = kx[j] - px0, dy = ky[j] - py0, dz = kz[j] - pz0;
        af0[j] = (__bf16)__builtin_amdgcn_sqrtf(dx * dx + dy * dy + dz * dz);
        dx = kx[j] - px1; dy = ky[j] - py1; dz = kz[j] - pz1;
        af1[j] = (__bf16)__builtin_amdgcn_sqrtf(dx * dx + dy * dy + dz * dz);
      }
#pragma unroll
      for (int t = 0; t < 4; ++t) {
        int f = t * 16 + fx;
        const float* wr = W + (size_t)f * N_PTS + G * 8;
        BF8 bw;
#pragma unroll
        for (int j = 0; j < 8; ++j) bw.v[j] = (__bf16)wr[j];
        acc[0][t] = __builtin_amdgcn_mfma_f32_16x16x32_bf16(af0, bw.v, acc[0][t], 0, 0, 0);
        acc[1][t] = __builtin_amdgcn_mfma_f32_16x16x32_bf16(af1, bw.v, acc[1][t], 0, 0, 0);
      }
    }
  }

  // ---- 8-way K-merge via LDS tree (4 regions x 512 f32x4) ----
  auto wr = [&](int rg) {
#pragma unroll
    for (int a = 0; a < 2; ++a)
#pragma unroll
      for (int t = 0; t < 4; ++t)
        mbuf[rg * 512 + (a * 4 + t) * 64 + lane] = acc[a][t];
  };
  auto rd = [&](int rg) {
#pragma unroll
    for (int a = 0; a < 2; ++a)
#pragma unroll
      for (int t = 0; t < 4; ++t)
        acc[a][t] += mbuf[rg * 512 + (a * 4 + t) * 64 + lane];
  };
  if (wave >= 4) wr(wave - 4);
  __syncthreads();
  if (wave < 4) rd(wave);
  __syncthreads();
  if (wave == 2 || wave == 3) wr(wave - 2);
  __syncthreads();
  if (wave < 2) rd(wave);
  __syncthreads();
  if (wave == 1) wr(0);
  __syncthreads();

  if (wave == 0) {
    rd(0);
    // epilogue: bias + LayerNorm(64) + SiLU. C/D layout: col=lane&15, row=q*4+r.
    float bb[4], gg[4], be[4];
#pragma unroll
    for (int t = 0; t < 4; ++t) {
      bb[t] = bias[t * 16 + fx];
      gg[t] = gamma[t * 16 + fx];
      be[t] = beta[t * 16 + fx];
    }
    float* outB = out + ((size_t)batch * N_PTS + rb) * FEATD;
#pragma unroll
    for (int a = 0; a < 2; ++a) {
#pragma unroll
      for (int r = 0; r < 4; ++r) {
        float x[4], d[4];
#pragma unroll
        for (int t = 0; t < 4; ++t) x[t] = acc[a][t][r] + bb[t];
        float s = x[0] + x[1] + x[2] + x[3];
        s += __shfl_xor(s, 1); s += __shfl_xor(s, 2);
        s += __shfl_xor(s, 4); s += __shfl_xor(s, 8);
        float mu = s * (1.f / 64.f);
        float v = 0.f;
#pragma unroll
        for (int t = 0; t < 4; ++t) { d[t] = x[t] - mu; v += d[t] * d[t]; }
        v += __shfl_xor(v, 1); v += __shfl_xor(v, 2);
        v += __shfl_xor(v, 4); v += __shfl_xor(v, 8);
        float rstd = __builtin_amdgcn_rsqf(v * (1.f / 64.f) + 1e-5f);
        float* orow = outB + (a * 16 + q * 4 + r) * FEATD;
#pragma unroll
        for (int t = 0; t < 4; ++t) {
          float xn = d[t] * rstd * gg[t] + be[t];
          float y = xn * (1.f / (1.f + __expf(-xn)));  // SiLU
          orow[t * 16 + fx] = y;
        }
      }
    }
  }
}

extern "C" void kernel_launch(void* const* d_in, const int* in_sizes, int n_in,
                              void* d_out, int out_size, void* d_ws, size_t ws_size,
                              hipStream_t stream) {
  const float* pos   = (const float*)d_in[0];  // (4,4096,3)
  const float* W     = (const float*)d_in[1];  // (64,4096)
  const float* bias  = (const float*)d_in[2];  // (64,)
  const float* gamma = (const float*)d_in[3];  // (64,)
  const float* beta  = (const float*)d_in[4];  // (64,)
  float* out = (float*)d_out;                  // (4,4096,64)

  const size_t wb_bytes = (size_t)FEATD * N_PTS * sizeof(unsigned short);  // 512 KiB
  const size_t pt_bytes = (size_t)3 * 4 * N_PTS * sizeof(float);           // 192 KiB
  int use_ws = (d_ws != nullptr && ws_size >= wb_bytes + pt_bytes);
  unsigned short* Wbt = use_ws ? (unsigned short*)d_ws : nullptr;
  float* Pt = use_ws ? (float*)((char*)d_ws + wb_bytes) : nullptr;

  if (use_ws) {
    prep_kernel<<<dim3(144), dim3(256), 0, stream>>>(W, pos, Wbt, Pt);
  }
  frp_kernel<<<dim3(512), dim3(512), 0, stream>>>(pos, W, bias, gamma, beta, Wbt, Pt, out);
}

// Round 7
// 92.765 us; speedup vs baseline: 3.9032x; 3.9032x over previous
//
#include <hip/hip_runtime.h>

// FeatureWithRelativePosition: fused pairwise-dist -> Linear(4096->64) -> LN -> SiLU
// BS=4, N=4096, FEAT=64. fp32 in/out, bf16 MFMA inner product, fp32 accumulate.
//
// R7: R6 structure (barrier-free K-loop, W read directly from L2-resident
//     bf16 transpose, LDS only for K-merge) with the spill fixed:
//     - __launch_bounds__(512,4): 128-VGPR cap (R6's (512,6)=85 cap spilled
//       acc/frags to scratch -> 589MB writes, 750MB fetches, 305us).
//     - fallback path moved to its own kernel so the hot kernel's register
//       allocation covers only the ws path.

typedef float f32x4 __attribute__((ext_vector_type(4)));
typedef __bf16 bf16x8 __attribute__((ext_vector_type(8)));

union BF8 { bf16x8 v; uint4 u; };

#define N_PTS 4096
#define FEATD 64

// ---- prep: blocks 0..127 convert W fp32 -> bf16 granule-major Wbt[512][64][8];
//      blocks 128..143 transpose pos -> Pt[coord][batch][4096] (SoA) ----
__global__ void prep_kernel(const float* __restrict__ W,
                            const float* __restrict__ pos,
                            unsigned short* __restrict__ Wbt,
                            float* __restrict__ Pt) {
  int b = blockIdx.x, t = threadIdx.x;  // 256 threads
  if (b < 128) {
    int gid = b * 256 + t;              // 32768 = 64 f * 512 G
    int f = gid >> 9, m8 = gid & 511;
    const float4* src = (const float4*)(W + (size_t)f * N_PTS + m8 * 8);
    float4 a = src[0], bb = src[1];
    BF8 o;
    o.v[0] = (__bf16)a.x;  o.v[1] = (__bf16)a.y;  o.v[2] = (__bf16)a.z;  o.v[3] = (__bf16)a.w;
    o.v[4] = (__bf16)bb.x; o.v[5] = (__bf16)bb.y; o.v[6] = (__bf16)bb.z; o.v[7] = (__bf16)bb.w;
    ((uint4*)Wbt)[(size_t)m8 * 64 + f] = o.u;
  } else {
    int bb = b - 128;          // 0..15
    int batch = bb >> 2, qtr = bb & 3;
    const float4* p4 = (const float4*)(pos + ((size_t)batch * N_PTS + qtr * 1024) * 3);
    float4 f0 = p4[t * 3 + 0], f1 = p4[t * 3 + 1], f2 = p4[t * 3 + 2];
    float4* Px = (float4*)(Pt + (size_t)(0 * 4 + batch) * N_PTS) + qtr * 256;
    float4* Py = (float4*)(Pt + (size_t)(1 * 4 + batch) * N_PTS) + qtr * 256;
    float4* Pz = (float4*)(Pt + (size_t)(2 * 4 + batch) * N_PTS) + qtr * 256;
    Px[t] = make_float4(f0.x, f0.w, f1.z, f2.y);
    Py[t] = make_float4(f0.y, f1.x, f1.w, f2.z);
    Pz[t] = make_float4(f0.z, f1.y, f2.x, f2.w);
  }
}

// ---- shared epilogue: 8-way K-merge + bias + LayerNorm + SiLU ----
__device__ __forceinline__ void merge_and_epilogue(
    f32x4 (&acc)[2][4], f32x4* mbuf, int wave, int lane, int fx, int q,
    int batch, int rb, const float* bias, const float* gamma,
    const float* beta, float* out) {
  auto wr = [&](int rg) {
#pragma unroll
    for (int a = 0; a < 2; ++a)
#pragma unroll
      for (int t = 0; t < 4; ++t)
        mbuf[rg * 512 + (a * 4 + t) * 64 + lane] = acc[a][t];
  };
  auto rd = [&](int rg) {
#pragma unroll
    for (int a = 0; a < 2; ++a)
#pragma unroll
      for (int t = 0; t < 4; ++t)
        acc[a][t] += mbuf[rg * 512 + (a * 4 + t) * 64 + lane];
  };
  if (wave >= 4) wr(wave - 4);
  __syncthreads();
  if (wave < 4) rd(wave);
  __syncthreads();
  if (wave == 2 || wave == 3) wr(wave - 2);
  __syncthreads();
  if (wave < 2) rd(wave);
  __syncthreads();
  if (wave == 1) wr(0);
  __syncthreads();

  if (wave == 0) {
    rd(0);
    float bb[4], gg[4], be[4];
#pragma unroll
    for (int t = 0; t < 4; ++t) {
      bb[t] = bias[t * 16 + fx];
      gg[t] = gamma[t * 16 + fx];
      be[t] = beta[t * 16 + fx];
    }
    float* outB = out + ((size_t)batch * N_PTS + rb) * FEATD;
#pragma unroll
    for (int a = 0; a < 2; ++a) {
#pragma unroll
      for (int r = 0; r < 4; ++r) {
        float x[4], d[4];
#pragma unroll
        for (int t = 0; t < 4; ++t) x[t] = acc[a][t][r] + bb[t];
        float s = x[0] + x[1] + x[2] + x[3];
        s += __shfl_xor(s, 1); s += __shfl_xor(s, 2);
        s += __shfl_xor(s, 4); s += __shfl_xor(s, 8);
        float mu = s * (1.f / 64.f);
        float v = 0.f;
#pragma unroll
        for (int t = 0; t < 4; ++t) { d[t] = x[t] - mu; v += d[t] * d[t]; }
        v += __shfl_xor(v, 1); v += __shfl_xor(v, 2);
        v += __shfl_xor(v, 4); v += __shfl_xor(v, 8);
        float rstd = __builtin_amdgcn_rsqf(v * (1.f / 64.f) + 1e-5f);
        float* orow = outB + (a * 16 + q * 4 + r) * FEATD;
#pragma unroll
        for (int t = 0; t < 4; ++t) {
          float xn = d[t] * rstd * gg[t] + be[t];
          float y = xn * (1.f / (1.f + __expf(-xn)));  // SiLU
          orow[t * 16 + fx] = y;
        }
      }
    }
  }
}

// grid = 512 (batch = bid>>7, rowblk = (bid&127)*32), block = 512 thr (8 waves).
// wave = K-slice (512 k each); every wave covers all 32 rows (2 rowtiles x 4 ftiles).
// No barriers in the K-loop; W/pos read via VMEM (L2/L1-resident).
__global__ __launch_bounds__(512, 4) void frp_kernel(
    const float* __restrict__ bias, const float* __restrict__ gamma,
    const float* __restrict__ beta, const unsigned short* __restrict__ Wbt,
    const float* __restrict__ Pt, float* __restrict__ out) {
  __shared__ f32x4 mbuf[4 * 512];   // 32 KiB merge buffer

  const int tid = threadIdx.x;
  const int lane = tid & 63;
  const int wave = tid >> 6;       // 0..7 = K-slice
  const int fx = lane & 15;
  const int q = lane >> 4;

  const int batch = blockIdx.x >> 7;
  const int rb = (blockIdx.x & 127) * 32;

  const float* PxG = Pt + (size_t)(0 * 4 + batch) * N_PTS;
  const float* PyG = Pt + (size_t)(1 * 4 + batch) * N_PTS;
  const float* PzG = Pt + (size_t)(2 * 4 + batch) * N_PTS;
  const uint4* Wq = (const uint4*)Wbt;

  f32x4 acc[2][4];
#pragma unroll
  for (int a = 0; a < 2; ++a)
#pragma unroll
    for (int t = 0; t < 4; ++t) acc[a][t] = (f32x4){0.f, 0.f, 0.f, 0.f};

  const int G0 = wave * 4 + q;     // this lane's first granule (8 k-pts)

  // A-row positions (2 rowtiles): rows rb + a*16 + fx
  const int n0 = rb + fx;
  const float px0 = PxG[n0],      py0 = PyG[n0],      pz0 = PzG[n0];
  const float px1 = PxG[n0 + 16], py1 = PyG[n0 + 16], pz1 = PzG[n0 + 16];

#pragma unroll 2
  for (int c = 0; c < 16; ++c) {
    const int G = c * 32 + G0;       // global granule
    const int m4 = G * 2;
    // 8 k-points (VMEM broadcast within quad, no barrier dependency)
    f32x4 xa = ((const f32x4*)PxG)[m4], xb = ((const f32x4*)PxG)[m4 + 1];
    f32x4 ya = ((const f32x4*)PyG)[m4], yb = ((const f32x4*)PyG)[m4 + 1];
    f32x4 za = ((const f32x4*)PzG)[m4], zb = ((const f32x4*)PzG)[m4 + 1];
    // 4 B-fragments: 64 consecutive uint4 per instr -> coalesced, L2-hit
    const uint4* wg = Wq + (size_t)G * 64 + fx;
    uint4 w0 = wg[0], w1 = wg[16], w2 = wg[32], w3 = wg[48];

    bf16x8 af0, af1;
    {
      f32x4 dx = xa - px0, dy = ya - py0, dz = za - pz0;
      f32x4 sq = dx * dx + dy * dy + dz * dz;
#pragma unroll
      for (int j = 0; j < 4; ++j) af0[j] = (__bf16)__builtin_amdgcn_sqrtf(sq[j]);
      dx = xb - px0; dy = yb - py0; dz = zb - pz0;
      sq = dx * dx + dy * dy + dz * dz;
#pragma unroll
      for (int j = 0; j < 4; ++j) af0[4 + j] = (__bf16)__builtin_amdgcn_sqrtf(sq[j]);
      dx = xa - px1; dy = ya - py1; dz = za - pz1;
      sq = dx * dx + dy * dy + dz * dz;
#pragma unroll
      for (int j = 0; j < 4; ++j) af1[j] = (__bf16)__builtin_amdgcn_sqrtf(sq[j]);
      dx = xb - px1; dy = yb - py1; dz = zb - pz1;
      sq = dx * dx + dy * dy + dz * dz;
#pragma unroll
      for (int j = 0; j < 4; ++j) af1[4 + j] = (__bf16)__builtin_amdgcn_sqrtf(sq[j]);
    }
    BF8 b0, b1, b2, b3;
    b0.u = w0; b1.u = w1; b2.u = w2; b3.u = w3;
    acc[0][0] = __builtin_amdgcn_mfma_f32_16x16x32_bf16(af0, b0.v, acc[0][0], 0, 0, 0);
    acc[1][0] = __builtin_amdgcn_mfma_f32_16x16x32_bf16(af1, b0.v, acc[1][0], 0, 0, 0);
    acc[0][1] = __builtin_amdgcn_mfma_f32_16x16x32_bf16(af0, b1.v, acc[0][1], 0, 0, 0);
    acc[1][1] = __builtin_amdgcn_mfma_f32_16x16x32_bf16(af1, b1.v, acc[1][1], 0, 0, 0);
    acc[0][2] = __builtin_amdgcn_mfma_f32_16x16x32_bf16(af0, b2.v, acc[0][2], 0, 0, 0);
    acc[1][2] = __builtin_amdgcn_mfma_f32_16x16x32_bf16(af1, b2.v, acc[1][2], 0, 0, 0);
    acc[0][3] = __builtin_amdgcn_mfma_f32_16x16x32_bf16(af0, b3.v, acc[0][3], 0, 0, 0);
    acc[1][3] = __builtin_amdgcn_mfma_f32_16x16x32_bf16(af1, b3.v, acc[1][3], 0, 0, 0);
  }

  merge_and_epilogue(acc, mbuf, wave, lane, fx, q, batch, rb,
                     bias, gamma, beta, out);
}

// ---- fallback (only if ws too small; correctness-only, separate kernel so it
//      doesn't inflate the hot kernel's register allocation) ----
__global__ __launch_bounds__(512) void frp_fallback_kernel(
    const float* __restrict__ pos, const float* __restrict__ W,
    const float* __restrict__ bias, const float* __restrict__ gamma,
    const float* __restrict__ beta, float* __restrict__ out) {
  __shared__ f32x4 mbuf[4 * 512];
  const int tid = threadIdx.x;
  const int lane = tid & 63;
  const int wave = tid >> 6;
  const int fx = lane & 15;
  const int q = lane >> 4;
  const int batch = blockIdx.x >> 7;
  const int rb = (blockIdx.x & 127) * 32;
  const float* posB = pos + (size_t)batch * N_PTS * 3;

  f32x4 acc[2][4];
#pragma unroll
  for (int a = 0; a < 2; ++a)
#pragma unroll
    for (int t = 0; t < 4; ++t) acc[a][t] = (f32x4){0.f, 0.f, 0.f, 0.f};

  const int G0 = wave * 4 + q;
  const int n0 = rb + fx;
  const float px0 = posB[n0 * 3], py0 = posB[n0 * 3 + 1], pz0 = posB[n0 * 3 + 2];
  const float px1 = posB[(n0 + 16) * 3], py1 = posB[(n0 + 16) * 3 + 1],
              pz1 = posB[(n0 + 16) * 3 + 2];

  for (int c = 0; c < 16; ++c) {
    const int G = c * 32 + G0;
    bf16x8 af0, af1;
#pragma unroll
    for (int j = 0; j < 8; ++j) {
      const float* pk = posB + ((size_t)G * 8 + j) * 3;
      float kx = pk[0], ky = pk[1], kz = pk[2];
      float dx = kx - px0, dy = ky - py0, dz = kz - pz0;
      af0[j] = (__bf16)__builtin_amdgcn_sqrtf(dx * dx + dy * dy + dz * dz);
      dx = kx - px1; dy = ky - py1; dz = kz - pz1;
      af1[j] = (__bf16)__builtin_amdgcn_sqrtf(dx * dx + dy * dy + dz * dz);
    }
#pragma unroll
    for (int t = 0; t < 4; ++t) {
      const float* wr = W + (size_t)(t * 16 + fx) * N_PTS + G * 8;
      BF8 bw;
#pragma unroll
      for (int j = 0; j < 8; ++j) bw.v[j] = (__bf16)wr[j];
      acc[0][t] = __builtin_amdgcn_mfma_f32_16x16x32_bf16(af0, bw.v, acc[0][t], 0, 0, 0);
      acc[1][t] = __builtin_amdgcn_mfma_f32_16x16x32_bf16(af1, bw.v, acc[1][t], 0, 0, 0);
    }
  }
  merge_and_epilogue(acc, mbuf, wave, lane, fx, q, batch, rb,
                     bias, gamma, beta, out);
}

extern "C" void kernel_launch(void* const* d_in, const int* in_sizes, int n_in,
                              void* d_out, int out_size, void* d_ws, size_t ws_size,
                              hipStream_t stream) {
  const float* pos   = (const float*)d_in[0];  // (4,4096,3)
  const float* W     = (const float*)d_in[1];  // (64,4096)
  const float* bias  = (const float*)d_in[2];  // (64,)
  const float* gamma = (const float*)d_in[3];  // (64,)
  const float* beta  = (const float*)d_in[4];  // (64,)
  float* out = (float*)d_out;                  // (4,4096,64)

  const size_t wb_bytes = (size_t)FEATD * N_PTS * sizeof(unsigned short);  // 512 KiB
  const size_t pt_bytes = (size_t)3 * 4 * N_PTS * sizeof(float);           // 192 KiB
  int use_ws = (d_ws != nullptr && ws_size >= wb_bytes + pt_bytes);

  if (use_ws) {
    unsigned short* Wbt = (unsigned short*)d_ws;
    float* Pt = (float*)((char*)d_ws + wb_bytes);
    prep_kernel<<<dim3(144), dim3(256), 0, stream>>>(W, pos, Wbt, Pt);
    frp_kernel<<<dim3(512), dim3(512), 0, stream>>>(bias, gamma, beta, Wbt, Pt, out);
  } else {
    frp_fallback_kernel<<<dim3(512), dim3(512), 0, stream>>>(pos, W, bias, gamma,
                                                             beta, out);
  }
}